// Round 5
// baseline (216.389 us; speedup 1.0000x reference)
//
#include <hip/hip_runtime.h>

// Multi-head attention, B=2 S=2048 D=768 H=12 DK=64. I/O fp32, internal bf16 MFMA.
// Round 12 = round 11 resubmitted verbatim (round-11 bench was an infra failure:
// container acquisition died twice; no kernel evidence). Audit confirmed bounds,
// barrier uniformity, and no new asm hazards.
// Round 11: launch-count + attn restructure.
//  - prep = cvt3 + transpose4 + maskscan merged (flat job decode): 7 -> 5 launches.
//  - K-gather deleted: attn reads K rows via idx[] indirection (128B contiguous
//    per row, LLC-resident); gatherV keeps only the V transpose/compact.
//  - attn: 128 keys per iteration (Kl[128][72], Vl[64][132]) — barriers halved,
//    two independent exp->pack->MFMA chains per iter for ILP. LDS 53KB, 3 blk/CU.
// Round 10: GEMM K-loop is a T3+T4 2-phase pipeline — double-buffered LDS (64KB),
// counted s_waitcnt vmcnt(8) + raw s_barrier (loads in flight across barriers).
// Mask compaction (round 9): ~50% keys masked (p=0 exactly); scan -> compact idx;
// attn has NO mask path (zero pad rows give p=1, corrected in denominator).
// Q pre-scaled by 0.125*log2(e) in QKV epilogue so softmax is raw v_exp_f32.
// Replay-hardening: idx/nk scratch in d_out (dead until final GEMM overwrites);
// no early return before barriers; no inline-asm transcendental fallbacks.
// Round-7 lesson: attn LDS arrays standalone + __align__(16); strides 72/132
// give optimal bank distribution for b128/b64 phases.

#define H_ 12
#define DK_ 64
#define B_DIM 2
#define SEQ 2048
#define DM 768
#define MROWS 4096
#define PER_IN ((size_t)MROWS * DM)
// 0.125 (1/sqrt(dk)) * log2(e): Q pre-scaled so attn uses raw v_exp_f32 = 2^x
#define QSCALE 0.18033688011112042f

typedef short bf16x8 __attribute__((ext_vector_type(8)));
typedef short bf16x4 __attribute__((ext_vector_type(4)));
typedef float f32x4 __attribute__((ext_vector_type(4)));
typedef float f32x16 __attribute__((ext_vector_type(16)));

__device__ inline unsigned short f2bf(float f) {
    union { float f; unsigned int i; } x; x.f = f;
    unsigned int r = x.i + 0x7fff + ((x.i >> 16) & 1); // RNE
    return (unsigned short)(r >> 16);
}

__device__ inline unsigned pack2bf(float lo, float hi) {
#if __has_builtin(__builtin_amdgcn_cvt_pk_bf16_f32)
    auto v = __builtin_amdgcn_cvt_pk_bf16_f32(lo, hi);
    return __builtin_bit_cast(unsigned, v);
#else
    return (unsigned)f2bf(lo) | ((unsigned)f2bf(hi) << 16);
#endif
}

__device__ inline float exp2fast(float x) { // 2^x
#if __has_builtin(__builtin_amdgcn_exp2f)
    return __builtin_amdgcn_exp2f(x);
#else
    return exp2f(x); // ocml native v_exp_f32; compiler-managed hazards
#endif
}

__device__ inline f32x16 mfma32x8(bf16x4 a, bf16x4 b, f32x16 c) {
#if __has_builtin(__builtin_amdgcn_mfma_f32_32x32x8bf16_1k)
    return __builtin_amdgcn_mfma_f32_32x32x8bf16_1k(a, b, c, 0, 0, 0);
#else
    asm("v_mfma_f32_32x32x8_bf16 %0, %1, %2, %0" : "+v"(c) : "v"(a), "v"(b));
    return c;
#endif
}

// async 16B/lane global->LDS; ldsbase must be wave-uniform (HW adds lane*16B)
__device__ inline void gload_lds16(const unsigned short* g, unsigned short* ldsbase,
                                   int lane) {
#if __has_builtin(__builtin_amdgcn_global_load_lds)
    __builtin_amdgcn_global_load_lds(
        (const __attribute__((address_space(1))) unsigned int*)g,
        (__attribute__((address_space(3))) unsigned int*)ldsbase, 16, 0, 0);
#else
    *(uint4*)(ldsbase + 8 * lane) = *(const uint4*)g;
#endif
}

// -------- prep: fp32->bf16 convert x3  |  4 weight transposes  |  mask scan ---
// Flat 1D grid, block-uniform job decode:
//   [0, 9216)        cvt: buf = job/3072, x = job%3072
//   [9216, 11520)    transpose: tb = job-9216; z = tb/576; by/bx from tb%576
//   [11520, 11522)   maskscan: b = job-11520
__global__ __launch_bounds__(256) void prep(
    const float* __restrict__ q, const float* __restrict__ k,
    const float* __restrict__ v,
    unsigned short* __restrict__ qb, unsigned short* __restrict__ kb,
    unsigned short* __restrict__ vb,
    const float* __restrict__ w0, const float* __restrict__ w1,
    const float* __restrict__ w2, const float* __restrict__ w3,
    unsigned short* __restrict__ wtbase,
    const int* __restrict__ mask, int* __restrict__ idx,
    int* __restrict__ nkeys) {
    __shared__ unsigned short t[32][33];
    __shared__ int wsum[4];
    int job = blockIdx.x, tid = threadIdx.x;
    if (job < 9216) { // ---- convert ----
        int buf = job / 3072, x = job % 3072;
        const float* src = buf == 0 ? q : (buf == 1 ? k : v);
        unsigned short* dst = buf == 0 ? qb : (buf == 1 ? kb : vb);
        size_t i = ((size_t)x * 256 + tid) * 4;
        float4 f = *(const float4*)(src + i);
        ushort4 u;
        u.x = f2bf(f.x); u.y = f2bf(f.y); u.z = f2bf(f.z); u.w = f2bf(f.w);
        *(ushort4*)(dst + i) = u;
    } else if (job < 11520) { // ---- weight transpose Wt[n][k] = bf16(W[k][n]) --
        int tb = job - 9216;
        int z = tb / 576, r = tb % 576, by = r / 24, bx = r % 24;
        const float* in = z == 0 ? w0 : (z == 1 ? w1 : (z == 2 ? w2 : w3));
        unsigned short* out = wtbase + (size_t)z * DM * DM;
        int x = tid & 31, y = tid >> 5; // 32 x 8
        int k0 = bx * 32, n0 = by * 32;
#pragma unroll
        for (int i = 0; i < 32; i += 8)
            t[y + i][x] = f2bf(in[(size_t)(k0 + y + i) * DM + n0 + x]);
        __syncthreads();
#pragma unroll
        for (int i = 0; i < 32; i += 8)
            out[(size_t)(n0 + y + i) * DM + k0 + x] = t[x][y + i];
    } else { // ---- mask scan: compact indices of unmasked keys ----
        int b = job - 11520;
        int lane = tid & 63, wave = tid >> 6;
        const int* mp = mask + (size_t)b * SEQ + tid * 8;
        int4 a = *(const int4*)mp;
        int4 c = *(const int4*)(mp + 4);
        int m[8] = {a.x, a.y, a.z, a.w, c.x, c.y, c.z, c.w};
        int pre[8], s = 0;
#pragma unroll
        for (int e = 0; e < 8; e++) { pre[e] = s; s += (m[e] != 0); }
        int incl = s;
#pragma unroll
        for (int off = 1; off < 64; off <<= 1) {
            int vv = __shfl_up(incl, off);
            if (lane >= off) incl += vv;
        }
        int lexcl = incl - s;
        if (lane == 63) wsum[wave] = incl;
        __syncthreads();
        int base = lexcl;
        for (int w = 0; w < wave; w++) base += wsum[w];
#pragma unroll
        for (int e = 0; e < 8; e++)
            if (m[e]) idx[b * SEQ + base + pre[e]] = tid * 8 + e;
        if (tid == 0) nkeys[b] = wsum[0] + wsum[1] + wsum[2] + wsum[3];
    }
}

// -------- gather compacted, transposed V columns, zero-padded to SEQ ---------
// Vtc[bh][d][j] = V[bh][idx[j]][d]; ALL blocks run, j >= n writes zeros.
__global__ __launch_bounds__(256) void gatherV(const unsigned short* __restrict__ Vn,
                                               const int* __restrict__ idx,
                                               const int* __restrict__ nkeys,
                                               unsigned short* __restrict__ Vtc) {
    __shared__ unsigned short Tl[64][72];
    int tid = threadIdx.x;
    int j0 = blockIdx.x * 64, bh = blockIdx.y, b = bh / H_;
    int n = nkeys[b];
    int row = tid >> 2, cb = (tid & 3) * 16;
    int j = j0 + row;
    int src = j < n ? idx[b * SEQ + j] : -1;
    unsigned short v[16];
    if (src >= 0) {
        const unsigned short* gv = Vn + ((size_t)bh * SEQ + src) * DK_ + cb;
        *(uint4*)&v[0] = *(const uint4*)gv;
        *(uint4*)&v[8] = *(const uint4*)(gv + 8);
    } else { // pad/tail: zero -> PV contribution 0
        uint4 z = {0u, 0u, 0u, 0u};
        *(uint4*)&v[0] = z;
        *(uint4*)&v[8] = z;
    }
#pragma unroll
    for (int e = 0; e < 16; e++)
        Tl[cb + e][row] = v[e];
    __syncthreads();
    uint4 o0 = *(const uint4*)&Tl[row][cb];
    uint4 o1 = *(const uint4*)&Tl[row][cb + 8];
    unsigned short* out = Vtc + ((size_t)bh * DK_ + row) * SEQ + j0 + cb;
    *(uint4*)out = o0;
    *(uint4*)(out + 8) = o1;
}

// ---------------- GEMM: C[m][n] = A[m][:] . Wt[n][:] + bias[n] ----------------
// 2-phase pipeline: LDS double-buffer; stage(t+1) issued BEFORE waiting on
// tile t (vmcnt(8) = next tile's 8 loads remain in flight); raw s_barrier.
template <int QKV>
__global__ __launch_bounds__(256) void gemm128(
    const unsigned short* __restrict__ A0, const unsigned short* __restrict__ A1,
    const unsigned short* __restrict__ A2, const unsigned short* __restrict__ Wt,
    const float* __restrict__ bias0, const float* __restrict__ bias1,
    const float* __restrict__ bias2,
    void* __restrict__ O0, void* __restrict__ O1, void* __restrict__ O2) {
    __shared__ unsigned short S[2][2][128][64]; // [buf][A|B][row][col], 64KB
    const int K = DM;
    const int NT = K / 64; // 12
    int tid = threadIdx.x;
    int wave = tid >> 6, lane = tid & 63, quad = lane >> 4, l15 = lane & 15;
    int wr = wave >> 1, wc = wave & 1;
    int m0 = blockIdx.x * 128, n0 = blockIdx.y * 128;
    int lrow = lane >> 3, lcol = (lane & 7) * 8;

    int mi = 0, nb0 = n0;
    const unsigned short* A = A0;
    const float* bias = bias0;
    void* O = O0;
    if constexpr (QKV) {
        mi = n0 >= 1536 ? 2 : (n0 >= 768 ? 1 : 0);
        nb0 = n0 - mi * 768;
        A = mi == 0 ? A0 : (mi == 1 ? A1 : A2);
        bias = mi == 0 ? bias0 : (mi == 1 ? bias1 : bias2);
        O = mi == 0 ? O0 : (mi == 1 ? O1 : O2);
    }

    f32x4 acc[4][4];
#pragma unroll
    for (int i = 0; i < 4; i++)
#pragma unroll
        for (int j = 0; j < 4; j++)
#pragma unroll
            for (int r = 0; r < 4; r++) acc[i][j][r] = 0.f;

    const unsigned short* gA = A + (size_t)(m0 + 32 * wave + lrow) * K + lcol;
    const unsigned short* gB = Wt + (size_t)(n0 + 32 * wave + lrow) * K + lcol;

    // prologue: stage tile 0 into buf 0 (8 async loads per wave)
#pragma unroll
    for (int c = 0; c < 4; c++) {
        gload_lds16(gA + (size_t)8 * c * K, &S[0][0][32 * wave + 8 * c][0], lane);
        gload_lds16(gB + (size_t)8 * c * K, &S[0][1][32 * wave + 8 * c][0], lane);
    }

    for (int t = 0; t < NT; t++) {
        int cur = t & 1;
        if (t + 1 < NT) { // issue next tile, then wait only for current tile
            int k0 = (t + 1) * 64;
#pragma unroll
            for (int c = 0; c < 4; c++) {
                gload_lds16(gA + (size_t)8 * c * K + k0, &S[cur ^ 1][0][32 * wave + 8 * c][0], lane);
                gload_lds16(gB + (size_t)8 * c * K + k0, &S[cur ^ 1][1][32 * wave + 8 * c][0], lane);
            }
            asm volatile("s_waitcnt vmcnt(8)" ::: "memory");
        } else {
            asm volatile("s_waitcnt vmcnt(0)" ::: "memory");
        }
        __builtin_amdgcn_s_barrier(); // all waves' tile-t loads landed

        unsigned short (*Al)[64] = S[cur][0];
        unsigned short (*Bl)[64] = S[cur][1];
#pragma unroll
        for (int ks = 0; ks < 64; ks += 32) {
            bf16x8 af[4], bfr[4];
#pragma unroll
            for (int i = 0; i < 4; i++)
                af[i] = *(const bf16x8*)&Al[64 * wr + 16 * i + l15][ks + 8 * quad];
#pragma unroll
            for (int j = 0; j < 4; j++)
                bfr[j] = *(const bf16x8*)&Bl[64 * wc + 16 * j + l15][ks + 8 * quad];
#pragma unroll
            for (int i = 0; i < 4; i++)
#pragma unroll
                for (int j = 0; j < 4; j++)
                    acc[i][j] = __builtin_amdgcn_mfma_f32_16x16x32_bf16(af[i], bfr[j], acc[i][j], 0, 0, 0);
        }
        asm volatile("" ::: "memory");    // pin LDS reads above the barrier
        __builtin_amdgcn_s_barrier();     // safe to overwrite buf[cur] next iter
    }

    if constexpr (!QKV) {
#pragma unroll
        for (int j = 0; j < 4; j++) {
            int nn = nb0 + 64 * wc + 16 * j + l15;
            float bv = bias[nn];
#pragma unroll
            for (int i = 0; i < 4; i++)
#pragma unroll
                for (int r = 0; r < 4; r++) {
                    int m = m0 + 64 * wr + 16 * i + 4 * quad + r;
                    ((float*)O0)[(size_t)m * DM + nn] = acc[i][j][r] + bv;
                }
        }
    } else {
        float sc = mi == 0 ? QSCALE : 1.0f; // bake softmax scale+log2e into Q
        __syncthreads();
        unsigned short (*Cl)[128] = (unsigned short(*)[128])S; // 32KB, fits S[0]
#pragma unroll
        for (int j = 0; j < 4; j++) {
            float bv = bias[nb0 + 64 * wc + 16 * j + l15];
#pragma unroll
            for (int i = 0; i < 4; i++)
#pragma unroll
                for (int r = 0; r < 4; r++)
                    Cl[64 * wr + 16 * i + 4 * quad + r][64 * wc + 16 * j + l15] =
                        f2bf((acc[i][j][r] + bv) * sc);
        }
        __syncthreads();
        int row = tid >> 1, half = tid & 1;
        int m = m0 + row;
        int b = m >> 11, s = m & 2047;
        int h = (nb0 + 64 * half) >> 6;
        unsigned short* og = (unsigned short*)O + ((size_t)(b * H_ + h) * SEQ + s) * DK_;
        const unsigned short* cr = &Cl[row][64 * half];
#pragma unroll
        for (int c = 0; c < 4; c++)
            *(uint4*)(og + 16 * c) = *(const uint4*)(cr + 16 * c);
#pragma unroll
        for (int c = 0; c < 4; c++)
            *(uint4*)(og + 16 * c + 8) = *(const uint4*)(cr + 16 * c + 8);
    }
}

// ------- flash attention, COMPACTED keys, idx-indirect K, 128-key tiles -------
// Q: (b,h,s,d) bf16 pre-scaled; Kh: (b,h,s,d) full (read via idx);
// Vtc: (b,h,d,j) compact; ctx: (b,s,h*d) bf16. No mask in inner loop:
// pad keys give K row = 0 -> p=1, corrected by subtracting pad count from l.
__global__ __launch_bounds__(256) void attn_fa(const unsigned short* __restrict__ Q,
                                               const unsigned short* __restrict__ Kh,
                                               const unsigned short* __restrict__ Vtc,
                                               const int* __restrict__ idx,
                                               const int* __restrict__ nkeys,
                                               unsigned short* __restrict__ ctx) {
    __shared__ __align__(16) unsigned short Ql[64][72];
    __shared__ __align__(16) unsigned short Kl[128][72];
    __shared__ __align__(16) unsigned short Vl[64][132];
    __shared__ __align__(16) float Op[2][32][32]; // epilogue partials, per d-half
    __shared__ __align__(16) float lp[2][32];     // kh=1 partial row sums
    int tid = threadIdx.x;
    int wave = tid >> 6, lane = tid & 63;
    int l31 = lane & 31, hi = lane >> 5;
    int qh = wave & 1, kh = wave >> 1; // q-half, key-half
    int bh = blockIdx.y, b = bh / H_, h = bh % H_;
    int q0 = blockIdx.x * 64;

    int n = nkeys[b];
    int nt = (n + 127) >> 7;            // 128-key tiles
    float padf = (float)(nt * 128 - n); // zero-pad keys contribute p=1 each

    { // stage Q tile (64x64) once
        int row = tid >> 2, cb = (tid & 3) * 16;
        const unsigned short* gq = Q + ((size_t)bh * SEQ + q0 + row) * DK_ + cb;
        *(uint4*)&Ql[row][cb]     = *(const uint4*)gq;
        *(uint4*)&Ql[row][cb + 8] = *(const uint4*)(gq + 8);
    }
    __syncthreads(); // Ql staged

    // loop-invariant Q fragments (queries 32*qh + l31)
    bf16x8 qf[4];
#pragma unroll
    for (int c = 0; c < 4; c++)
        qf[c] = *(const bf16x8*)&Ql[32 * qh + l31][16 * c + 8 * hi];

    float lrow = 0.f; // per-lane (q = l31) partial row sum over this wave's keys
    f32x16 o[2][2];   // [d-half][ilp]; summed at end
#pragma unroll
    for (int dt = 0; dt < 2; dt++)
#pragma unroll
        for (int p = 0; p < 2; p++)
#pragma unroll
            for (int r = 0; r < 16; r++) o[dt][p][r] = 0.f;

    int krow = tid >> 1, kof = (tid & 1) * 32; // K: 128 rows x 64B per thread-pair
    int vrow = tid >> 2, vof = (tid & 3) * 32; // V: 64 d-rows x 256B, 4 thr/row
    const int* idxb = idx + (size_t)b * SEQ;
    const unsigned short* gvb = Vtc + ((size_t)bh * DK_ + vrow) * SEQ + vof;

    uint4 kr[4], vr[4];
    { // prefetch tile 0
        int src = (krow < n) ? idxb[krow] : -1;
        if (src >= 0) {
            const unsigned short* gk = Kh + ((size_t)bh * SEQ + src) * DK_ + kof;
#pragma unroll
            for (int e = 0; e < 4; e++) kr[e] = *(const uint4*)(gk + 8 * e);
        } else {
            uint4 z = {0u, 0u, 0u, 0u};
#pragma unroll
            for (int e = 0; e < 4; e++) kr[e] = z;
        }
#pragma unroll
        for (int e = 0; e < 4; e++) vr[e] = *(const uint4*)(gvb + 8 * e);
    }

    for (int kt = 0; kt < nt; kt++) {
        __syncthreads(); // prev iter's K/V LDS reads done
#pragma unroll
        for (int e = 0; e < 4; e++) *(uint4*)&Kl[krow][kof + 8 * e] = kr[e];
#pragma unroll
        for (int e = 0; e < 4; e++) *(uint4*)&Vl[vrow][vof + 8 * e] = vr[e];
        __syncthreads(); // tiles visible
        if (kt + 1 < nt) { // prefetch next (latency hidden under compute)
            int j = (kt + 1) * 128 + krow;
            int src = (j < n) ? idxb[j] : -1;
            if (src >= 0) {
                const unsigned short* gk = Kh + ((size_t)bh * SEQ + src) * DK_ + kof;
#pragma unroll
                for (int e = 0; e < 4; e++) kr[e] = *(const uint4*)(gk + 8 * e);
            } else {
                uint4 z = {0u, 0u, 0u, 0u};
#pragma unroll
                for (int e = 0; e < 4; e++) kr[e] = z;
            }
            const unsigned short* gvn = gvb + (size_t)(kt + 1) * 128;
#pragma unroll
            for (int e = 0; e < 4; e++) vr[e] = *(const uint4*)(gvn + 8 * e);
        }

        // two independent 64-key chains (kb = 0,1): ILP across exp chains
#pragma unroll
        for (int kb = 0; kb < 2; kb++) {
            // S^T = K.Q^T (32 keys x 32 queries for this wave); zero C-init
            f32x16 sT;
#pragma unroll
            for (int r = 0; r < 16; r++) sT[r] = 0.f;
#pragma unroll
            for (int c = 0; c < 4; c++) {
                bf16x8 kf = *(const bf16x8*)&Kl[64 * kb + 32 * kh + l31][16 * c + 8 * hi];
                sT = __builtin_amdgcn_mfma_f32_32x32x16_bf16(kf, qf[c], sT, 0, 0, 0);
            }

            // p = 2^s (scale pre-baked into Q): regs ARE the PV MFMA A-operand
            bf16x4 pfrag[4];
#pragma unroll
            for (int c = 0; c < 4; c++) {
                float p0 = exp2fast(sT[4 * c + 0]);
                float p1 = exp2fast(sT[4 * c + 1]);
                float p2 = exp2fast(sT[4 * c + 2]);
                float p3 = exp2fast(sT[4 * c + 3]);
                lrow += (p0 + p1) + (p2 + p3);
                union { unsigned u[2]; bf16x4 v; } pk;
                pk.u[0] = pack2bf(p0, p1);
                pk.u[1] = pack2bf(p2, p3);
                pfrag[c] = pk.v;
            }

            // O[q][d] += P.V over this wave's 32 keys of block kb
#pragma unroll
            for (int dt = 0; dt < 2; dt++)
#pragma unroll
                for (int c = 0; c < 4; c++) {
                    bf16x4 vf = *(const bf16x4*)&Vl[32 * dt + l31][64 * kb + 32 * kh + 8 * c + 4 * hi];
                    o[dt][c & 1] = mfma32x8(pfrag[c], vf, o[dt][c & 1]);
                }
        }
    }

    // combine across key-half wave pairs (two d-half chunks through Op), store
    lrow += __shfl_xor(lrow, 32); // both hi-halves hold full partial for q=l31
    float inv = 0.f;
#pragma unroll
    for (int dt = 0; dt < 2; dt++) {
        if (kh == 1) {
#pragma unroll
            for (int r = 0; r < 16; r++) {
                int qrl = (r & 3) + 8 * (r >> 2) + 4 * hi;
                Op[qh][qrl][l31] = o[dt][0][r] + o[dt][1][r];
            }
            if (dt == 0 && hi == 0) lp[qh][l31] = lrow;
        }
        __syncthreads();
        if (kh == 0) {
            if (dt == 0) {
                float l = lrow + lp[qh][l31] - padf; // remove pad-key p=1 terms
                inv = l > 0.f ? 1.f / l : 0.f;
            }
#pragma unroll
            for (int r = 0; r < 16; r++) {
                int qrl = (r & 3) + 8 * (r >> 2) + 4 * hi;
                float invr = __shfl(inv, qrl); // inv lives at lane q
                int qg = q0 + 32 * qh + qrl;
                size_t base = ((size_t)b * SEQ + qg) * DM + h * DK_;
                float v = o[dt][0][r] + o[dt][1][r] + Op[qh][qrl][l31];
                ctx[base + 32 * dt + l31] = f2bf(v * invr);
            }
        }
        __syncthreads(); // Op safe for next chunk
    }
}

extern "C" void kernel_launch(void* const* d_in, const int* in_sizes, int n_in,
                              void* d_out, int out_size, void* d_ws, size_t ws_size,
                              hipStream_t stream) {
    const float* q  = (const float*)d_in[0];
    const float* k  = (const float*)d_in[1];
    const float* v  = (const float*)d_in[2];
    const float* Wq = (const float*)d_in[3];
    const float* bq = (const float*)d_in[4];
    const float* Wk = (const float*)d_in[5];
    const float* bk = (const float*)d_in[6];
    const float* Wv = (const float*)d_in[7];
    const float* bv = (const float*)d_in[8];
    const float* Wo = (const float*)d_in[9];
    const float* bo = (const float*)d_in[10];
    const int* mask = (const int*)d_in[11];

    unsigned short* ws = (unsigned short*)d_ws;
    unsigned short* qb = ws;
    unsigned short* kb = ws + PER_IN;
    unsigned short* vb = ws + 2 * PER_IN;
    unsigned short* Qh = ws + 3 * PER_IN;
    unsigned short* Kh = ws + 4 * PER_IN;
    unsigned short* Vhn = ws + 5 * PER_IN;
    unsigned short* WtQKV = ws + 6 * PER_IN;
    unsigned short* WtO = WtQKV + (size_t)3 * DM * DM;
    unsigned short* Vtc = vb;  // vb dead after QKV GEMM
    unsigned short* ctx = qb;  // qb dead after QKV GEMM
    // idx/nk scratch lives at the head of d_out: dead by the time the output
    // GEMM (the only d_out writer) runs; avoids aliasing live weight buffers.
    int* idx = (int*)d_out;
    int* nk = idx + B_DIM * SEQ;

    // prep: 9216 cvt blocks + 2304 transpose blocks + 2 scan blocks
    prep<<<dim3(11522), 256, 0, stream>>>(q, k, v, qb, kb, vb,
                                          Wq, Wk, Wv, Wo, WtQKV, mask, idx, nk);

    gemm128<1><<<dim3(MROWS / 128, 3 * DM / 128), 256, 0, stream>>>(
        qb, kb, vb, WtQKV, bq, bk, bv, Qh, Kh, Vhn);

    gatherV<<<dim3(SEQ / 64, B_DIM * H_), 256, 0, stream>>>(Vhn, idx, nk, Vtc);

    attn_fa<<<dim3(SEQ / 64, B_DIM * H_), 256, 0, stream>>>(Qh, Kh, Vtc, idx, nk, ctx);

    gemm128<0><<<dim3(MROWS / 128, DM / 128), 256, 0, stream>>>(
        ctx, ctx, ctx, WtO, bo, bo, bo, d_out, d_out, d_out);
}

// Round 6
// 192.956 us; speedup vs baseline: 1.1214x; 1.1214x over previous
//
#include <hip/hip_runtime.h>

// Multi-head attention, B=2 S=2048 D=768 H=12 DK=64. I/O fp32, internal bf16 MFMA.
// Round 13: revert round-11/12 attn regression (idx-indirect K + 128-key tiles
// was 2x SLOWER: 65us, MfmaUtil 11.7%, latency-bound on in-loop scatter chain
// idx->K row; bank conflicts 49K->835K). Restored: round-9 gatherKV (scatter paid
// ONCE, streaming, off critical path) + round-9 attn (64-key tiles, sequential
// compact reads, proven LDS strides 72/68). Kept from round 11: merged prep
// (cvt3+transpose4+maskscan, 5 launches total).
// Round 10: GEMM K-loop is a T3+T4 2-phase pipeline — double-buffered LDS (64KB),
// counted s_waitcnt vmcnt(8) + raw s_barrier (loads in flight across barriers).
// Mask compaction (round 9): ~50% keys masked (p=0 exactly); scan -> compact idx;
// attn has NO mask path (zero pad rows give p=1, corrected in denominator).
// Q pre-scaled by 0.125*log2(e) in QKV epilogue so softmax is raw v_exp_f32.
// Replay-hardening: idx/nk scratch in d_out (dead until final GEMM overwrites);
// no early return before barriers; no inline-asm transcendental fallbacks.
// Round-7 lesson: attn LDS arrays standalone + __align__(16), strides 72/68.

#define H_ 12
#define DK_ 64
#define B_DIM 2
#define SEQ 2048
#define DM 768
#define MROWS 4096
#define PER_IN ((size_t)MROWS * DM)
// 0.125 (1/sqrt(dk)) * log2(e): Q pre-scaled so attn uses raw v_exp_f32 = 2^x
#define QSCALE 0.18033688011112042f

typedef short bf16x8 __attribute__((ext_vector_type(8)));
typedef short bf16x4 __attribute__((ext_vector_type(4)));
typedef float f32x4 __attribute__((ext_vector_type(4)));
typedef float f32x16 __attribute__((ext_vector_type(16)));

__device__ inline unsigned short f2bf(float f) {
    union { float f; unsigned int i; } x; x.f = f;
    unsigned int r = x.i + 0x7fff + ((x.i >> 16) & 1); // RNE
    return (unsigned short)(r >> 16);
}

__device__ inline unsigned pack2bf(float lo, float hi) {
#if __has_builtin(__builtin_amdgcn_cvt_pk_bf16_f32)
    auto v = __builtin_amdgcn_cvt_pk_bf16_f32(lo, hi);
    return __builtin_bit_cast(unsigned, v);
#else
    return (unsigned)f2bf(lo) | ((unsigned)f2bf(hi) << 16);
#endif
}

__device__ inline float exp2fast(float x) { // 2^x
#if __has_builtin(__builtin_amdgcn_exp2f)
    return __builtin_amdgcn_exp2f(x);
#else
    return exp2f(x); // ocml native v_exp_f32; compiler-managed hazards
#endif
}

__device__ inline f32x16 mfma32x8(bf16x4 a, bf16x4 b, f32x16 c) {
#if __has_builtin(__builtin_amdgcn_mfma_f32_32x32x8bf16_1k)
    return __builtin_amdgcn_mfma_f32_32x32x8bf16_1k(a, b, c, 0, 0, 0);
#else
    asm("v_mfma_f32_32x32x8_bf16 %0, %1, %2, %0" : "+v"(c) : "v"(a), "v"(b));
    return c;
#endif
}

// async 16B/lane global->LDS; ldsbase must be wave-uniform (HW adds lane*16B)
__device__ inline void gload_lds16(const unsigned short* g, unsigned short* ldsbase,
                                   int lane) {
#if __has_builtin(__builtin_amdgcn_global_load_lds)
    __builtin_amdgcn_global_load_lds(
        (const __attribute__((address_space(1))) unsigned int*)g,
        (__attribute__((address_space(3))) unsigned int*)ldsbase, 16, 0, 0);
#else
    *(uint4*)(ldsbase + 8 * lane) = *(const uint4*)g;
#endif
}

// -------- prep: fp32->bf16 convert x3  |  4 weight transposes  |  mask scan ---
// Flat 1D grid, block-uniform job decode:
//   [0, 9216)        cvt: buf = job/3072, x = job%3072
//   [9216, 11520)    transpose: tb = job-9216; z = tb/576; by/bx from tb%576
//   [11520, 11522)   maskscan: b = job-11520
__global__ __launch_bounds__(256) void prep(
    const float* __restrict__ q, const float* __restrict__ k,
    const float* __restrict__ v,
    unsigned short* __restrict__ qb, unsigned short* __restrict__ kb,
    unsigned short* __restrict__ vb,
    const float* __restrict__ w0, const float* __restrict__ w1,
    const float* __restrict__ w2, const float* __restrict__ w3,
    unsigned short* __restrict__ wtbase,
    const int* __restrict__ mask, int* __restrict__ idx,
    int* __restrict__ nkeys) {
    __shared__ unsigned short t[32][33];
    __shared__ int wsum[4];
    int job = blockIdx.x, tid = threadIdx.x;
    if (job < 9216) { // ---- convert ----
        int buf = job / 3072, x = job % 3072;
        const float* src = buf == 0 ? q : (buf == 1 ? k : v);
        unsigned short* dst = buf == 0 ? qb : (buf == 1 ? kb : vb);
        size_t i = ((size_t)x * 256 + tid) * 4;
        float4 f = *(const float4*)(src + i);
        ushort4 u;
        u.x = f2bf(f.x); u.y = f2bf(f.y); u.z = f2bf(f.z); u.w = f2bf(f.w);
        *(ushort4*)(dst + i) = u;
    } else if (job < 11520) { // ---- weight transpose Wt[n][k] = bf16(W[k][n]) --
        int tb = job - 9216;
        int z = tb / 576, r = tb % 576, by = r / 24, bx = r % 24;
        const float* in = z == 0 ? w0 : (z == 1 ? w1 : (z == 2 ? w2 : w3));
        unsigned short* out = wtbase + (size_t)z * DM * DM;
        int x = tid & 31, y = tid >> 5; // 32 x 8
        int k0 = bx * 32, n0 = by * 32;
#pragma unroll
        for (int i = 0; i < 32; i += 8)
            t[y + i][x] = f2bf(in[(size_t)(k0 + y + i) * DM + n0 + x]);
        __syncthreads();
#pragma unroll
        for (int i = 0; i < 32; i += 8)
            out[(size_t)(n0 + y + i) * DM + k0 + x] = t[x][y + i];
    } else { // ---- mask scan: compact indices of unmasked keys ----
        int b = job - 11520;
        int lane = tid & 63, wave = tid >> 6;
        const int* mp = mask + (size_t)b * SEQ + tid * 8;
        int4 a = *(const int4*)mp;
        int4 c = *(const int4*)(mp + 4);
        int m[8] = {a.x, a.y, a.z, a.w, c.x, c.y, c.z, c.w};
        int pre[8], s = 0;
#pragma unroll
        for (int e = 0; e < 8; e++) { pre[e] = s; s += (m[e] != 0); }
        int incl = s;
#pragma unroll
        for (int off = 1; off < 64; off <<= 1) {
            int vv = __shfl_up(incl, off);
            if (lane >= off) incl += vv;
        }
        int lexcl = incl - s;
        if (lane == 63) wsum[wave] = incl;
        __syncthreads();
        int base = lexcl;
        for (int w = 0; w < wave; w++) base += wsum[w];
#pragma unroll
        for (int e = 0; e < 8; e++)
            if (m[e]) idx[b * SEQ + base + pre[e]] = tid * 8 + e;
        if (tid == 0) nkeys[b] = wsum[0] + wsum[1] + wsum[2] + wsum[3];
    }
}

// -------- gather compacted K rows + transposed V columns, zero-padded --------
// Kc[bh][j][d] = Kh[bh][idx[j]][d];  Vtc[bh][d][j] = V[bh][idx[j]][d]
// ALL blocks run; j >= n writes zeros (deterministic state, no early return).
// Scatter cost paid ONCE here (streaming), keeping attn's inner loop sequential.
__global__ __launch_bounds__(256) void gatherKV(const unsigned short* __restrict__ Kh,
                                                const unsigned short* __restrict__ Vn,
                                                const int* __restrict__ idx,
                                                const int* __restrict__ nkeys,
                                                unsigned short* __restrict__ Kc,
                                                unsigned short* __restrict__ Vtc) {
    __shared__ unsigned short Tl[64][72];
    int tid = threadIdx.x;
    int j0 = blockIdx.x * 64, bh = blockIdx.y, b = bh / H_;
    int n = nkeys[b];
    int row = tid >> 2, cb = (tid & 3) * 16;
    int j = j0 + row;
    int src = j < n ? idx[b * SEQ + j] : -1;
    unsigned short v[16];
    unsigned short* ok = Kc + ((size_t)bh * SEQ + j) * DK_ + cb;
    if (src >= 0) {
        const unsigned short* gv = Vn + ((size_t)bh * SEQ + src) * DK_ + cb;
        *(uint4*)&v[0] = *(const uint4*)gv;
        *(uint4*)&v[8] = *(const uint4*)(gv + 8);
        const unsigned short* gk = Kh + ((size_t)bh * SEQ + src) * DK_ + cb;
        uint4 k0 = *(const uint4*)gk;
        uint4 k1 = *(const uint4*)(gk + 8);
        *(uint4*)ok = k0;
        *(uint4*)(ok + 8) = k1;
    } else { // pad/tail: zero K row and V row -> s=0, p=1 (corrected), p*V=0
        uint4 z = {0u, 0u, 0u, 0u};
        *(uint4*)&v[0] = z;
        *(uint4*)&v[8] = z;
        *(uint4*)ok = z;
        *(uint4*)(ok + 8) = z;
    }
#pragma unroll
    for (int e = 0; e < 16; e++)
        Tl[cb + e][row] = v[e];
    __syncthreads();
    uint4 o0 = *(const uint4*)&Tl[row][cb];
    uint4 o1 = *(const uint4*)&Tl[row][cb + 8];
    unsigned short* out = Vtc + ((size_t)bh * DK_ + row) * SEQ + j0 + cb;
    *(uint4*)out = o0;
    *(uint4*)(out + 8) = o1;
}

// ---------------- GEMM: C[m][n] = A[m][:] . Wt[n][:] + bias[n] ----------------
// 2-phase pipeline: LDS double-buffer; stage(t+1) issued BEFORE waiting on
// tile t (vmcnt(8) = next tile's 8 loads remain in flight); raw s_barrier.
template <int QKV>
__global__ __launch_bounds__(256) void gemm128(
    const unsigned short* __restrict__ A0, const unsigned short* __restrict__ A1,
    const unsigned short* __restrict__ A2, const unsigned short* __restrict__ Wt,
    const float* __restrict__ bias0, const float* __restrict__ bias1,
    const float* __restrict__ bias2,
    void* __restrict__ O0, void* __restrict__ O1, void* __restrict__ O2) {
    __shared__ unsigned short S[2][2][128][64]; // [buf][A|B][row][col], 64KB
    const int K = DM;
    const int NT = K / 64; // 12
    int tid = threadIdx.x;
    int wave = tid >> 6, lane = tid & 63, quad = lane >> 4, l15 = lane & 15;
    int wr = wave >> 1, wc = wave & 1;
    int m0 = blockIdx.x * 128, n0 = blockIdx.y * 128;
    int lrow = lane >> 3, lcol = (lane & 7) * 8;

    int mi = 0, nb0 = n0;
    const unsigned short* A = A0;
    const float* bias = bias0;
    void* O = O0;
    if constexpr (QKV) {
        mi = n0 >= 1536 ? 2 : (n0 >= 768 ? 1 : 0);
        nb0 = n0 - mi * 768;
        A = mi == 0 ? A0 : (mi == 1 ? A1 : A2);
        bias = mi == 0 ? bias0 : (mi == 1 ? bias1 : bias2);
        O = mi == 0 ? O0 : (mi == 1 ? O1 : O2);
    }

    f32x4 acc[4][4];
#pragma unroll
    for (int i = 0; i < 4; i++)
#pragma unroll
        for (int j = 0; j < 4; j++)
#pragma unroll
            for (int r = 0; r < 4; r++) acc[i][j][r] = 0.f;

    const unsigned short* gA = A + (size_t)(m0 + 32 * wave + lrow) * K + lcol;
    const unsigned short* gB = Wt + (size_t)(n0 + 32 * wave + lrow) * K + lcol;

    // prologue: stage tile 0 into buf 0 (8 async loads per wave)
#pragma unroll
    for (int c = 0; c < 4; c++) {
        gload_lds16(gA + (size_t)8 * c * K, &S[0][0][32 * wave + 8 * c][0], lane);
        gload_lds16(gB + (size_t)8 * c * K, &S[0][1][32 * wave + 8 * c][0], lane);
    }

    for (int t = 0; t < NT; t++) {
        int cur = t & 1;
        if (t + 1 < NT) { // issue next tile, then wait only for current tile
            int k0 = (t + 1) * 64;
#pragma unroll
            for (int c = 0; c < 4; c++) {
                gload_lds16(gA + (size_t)8 * c * K + k0, &S[cur ^ 1][0][32 * wave + 8 * c][0], lane);
                gload_lds16(gB + (size_t)8 * c * K + k0, &S[cur ^ 1][1][32 * wave + 8 * c][0], lane);
            }
            asm volatile("s_waitcnt vmcnt(8)" ::: "memory");
        } else {
            asm volatile("s_waitcnt vmcnt(0)" ::: "memory");
        }
        __builtin_amdgcn_s_barrier(); // all waves' tile-t loads landed

        unsigned short (*Al)[64] = S[cur][0];
        unsigned short (*Bl)[64] = S[cur][1];
#pragma unroll
        for (int ks = 0; ks < 64; ks += 32) {
            bf16x8 af[4], bfr[4];
#pragma unroll
            for (int i = 0; i < 4; i++)
                af[i] = *(const bf16x8*)&Al[64 * wr + 16 * i + l15][ks + 8 * quad];
#pragma unroll
            for (int j = 0; j < 4; j++)
                bfr[j] = *(const bf16x8*)&Bl[64 * wc + 16 * j + l15][ks + 8 * quad];
#pragma unroll
            for (int i = 0; i < 4; i++)
#pragma unroll
                for (int j = 0; j < 4; j++)
                    acc[i][j] = __builtin_amdgcn_mfma_f32_16x16x32_bf16(af[i], bfr[j], acc[i][j], 0, 0, 0);
        }
        asm volatile("" ::: "memory");    // pin LDS reads above the barrier
        __builtin_amdgcn_s_barrier();     // safe to overwrite buf[cur] next iter
    }

    if constexpr (!QKV) {
#pragma unroll
        for (int j = 0; j < 4; j++) {
            int nn = nb0 + 64 * wc + 16 * j + l15;
            float bv = bias[nn];
#pragma unroll
            for (int i = 0; i < 4; i++)
#pragma unroll
                for (int r = 0; r < 4; r++) {
                    int m = m0 + 64 * wr + 16 * i + 4 * quad + r;
                    ((float*)O0)[(size_t)m * DM + nn] = acc[i][j][r] + bv;
                }
        }
    } else {
        float sc = mi == 0 ? QSCALE : 1.0f; // bake softmax scale+log2e into Q
        __syncthreads();
        unsigned short (*Cl)[128] = (unsigned short(*)[128])S; // 32KB, fits S[0]
#pragma unroll
        for (int j = 0; j < 4; j++) {
            float bv = bias[nb0 + 64 * wc + 16 * j + l15];
#pragma unroll
            for (int i = 0; i < 4; i++)
#pragma unroll
                for (int r = 0; r < 4; r++)
                    Cl[64 * wr + 16 * i + 4 * quad + r][64 * wc + 16 * j + l15] =
                        f2bf((acc[i][j][r] + bv) * sc);
        }
        __syncthreads();
        int row = tid >> 1, half = tid & 1;
        int m = m0 + row;
        int b = m >> 11, s = m & 2047;
        int h = (nb0 + 64 * half) >> 6;
        unsigned short* og = (unsigned short*)O + ((size_t)(b * H_ + h) * SEQ + s) * DK_;
        const unsigned short* cr = &Cl[row][64 * half];
#pragma unroll
        for (int c = 0; c < 4; c++)
            *(uint4*)(og + 16 * c) = *(const uint4*)(cr + 16 * c);
#pragma unroll
        for (int c = 0; c < 4; c++)
            *(uint4*)(og + 16 * c + 8) = *(const uint4*)(cr + 16 * c + 8);
    }
}

// ---------------- flash attention over COMPACTED keys, 2x2 wave split ---------
// Q: (b,h,s,d) bf16 pre-scaled; Kc: (b,h,j,d) compact; Vtc: (b,h,d,j) compact;
// nkeys: per-batch live-key count; ctx: (b,s,h*d) bf16. No mask in inner loop:
// pad rows are zero -> p=exp2(0)=1, corrected by subtracting pad count from l.
__global__ __launch_bounds__(256) void attn_fa(const unsigned short* __restrict__ Q,
                                               const unsigned short* __restrict__ Kc,
                                               const unsigned short* __restrict__ Vtc,
                                               const int* __restrict__ nkeys,
                                               unsigned short* __restrict__ ctx) {
    __shared__ __align__(16) unsigned short Ql[64][72];
    __shared__ __align__(16) unsigned short Kl[64][72];
    __shared__ __align__(16) unsigned short Vl[64][68];
    __shared__ __align__(16) float Op[2][32][32]; // epilogue partials, per d-half
    __shared__ __align__(16) float lp[2][32];     // kh=1 partial row sums
    int tid = threadIdx.x;
    int wave = tid >> 6, lane = tid & 63;
    int l31 = lane & 31, hi = lane >> 5;
    int qh = wave & 1, kh = wave >> 1; // q-half, key-half
    int bh = blockIdx.y, b = bh / H_, h = bh % H_;
    int q0 = blockIdx.x * 64;

    int n = nkeys[b];
    int nt = (n + 63) >> 6;            // compacted key tiles
    float padf = (float)(nt * 64 - n); // zero-pad rows contribute p=1 each

    { // stage Q tile (64x64) once
        int row = tid >> 2, cb = (tid & 3) * 16;
        const unsigned short* gq = Q + ((size_t)bh * SEQ + q0 + row) * DK_ + cb;
        *(uint4*)&Ql[row][cb]     = *(const uint4*)gq;
        *(uint4*)&Ql[row][cb + 8] = *(const uint4*)(gq + 8);
    }
    __syncthreads(); // Ql staged

    // loop-invariant Q fragments (queries 32*qh + l31)
    bf16x8 qf[4];
#pragma unroll
    for (int c = 0; c < 4; c++)
        qf[c] = *(const bf16x8*)&Ql[32 * qh + l31][16 * c + 8 * hi];

    float lrow = 0.f; // per-lane (q = l31) partial row sum over this wave's keys
    f32x16 o[2][2];   // [d-half][ilp]; summed at end
#pragma unroll
    for (int dt = 0; dt < 2; dt++)
#pragma unroll
        for (int p = 0; p < 2; p++)
#pragma unroll
            for (int r = 0; r < 16; r++) o[dt][p][r] = 0.f;

    int krow = tid >> 2, kcb = (tid & 3) * 16;
    const unsigned short* gk = Kc + ((size_t)bh * SEQ + krow) * DK_ + kcb;
    const unsigned short* gv = Vtc + ((size_t)bh * DK_ + krow) * SEQ + kcb;

    // prefetch iter 0
    uint4 kr0 = *(const uint4*)gk, kr1 = *(const uint4*)(gk + 8);
    uint4 vr0 = *(const uint4*)gv, vr1 = *(const uint4*)(gv + 8);

    for (int kt = 0; kt < nt; kt++) {
        __syncthreads(); // prev iter's K/V LDS reads done
        *(uint4*)&Kl[krow][kcb]     = kr0;
        *(uint4*)&Kl[krow][kcb + 8] = kr1;
        *(uint4*)&Vl[krow][kcb]     = vr0;
        *(uint4*)&Vl[krow][kcb + 8] = vr1;
        __syncthreads(); // tiles visible
        if (kt + 1 < nt) { // prefetch next (latency hidden under compute)
            gk += (size_t)64 * DK_;
            gv += 64;
            kr0 = *(const uint4*)gk; kr1 = *(const uint4*)(gk + 8);
            vr0 = *(const uint4*)gv; vr1 = *(const uint4*)(gv + 8);
        }

        // S^T = K.Q^T (32 keys x 32 queries for this wave); zero C-init, no mask
        f32x16 sT;
#pragma unroll
        for (int r = 0; r < 16; r++) sT[r] = 0.f;
#pragma unroll
        for (int c = 0; c < 4; c++) {
            bf16x8 kf = *(const bf16x8*)&Kl[32 * kh + l31][16 * c + 8 * hi];
            sT = __builtin_amdgcn_mfma_f32_32x32x16_bf16(kf, qf[c], sT, 0, 0, 0);
        }

        // p = 2^s (scale pre-baked into Q): regs ARE the PV MFMA A-operand
        bf16x4 pfrag[4];
#pragma unroll
        for (int c = 0; c < 4; c++) {
            float p0 = exp2fast(sT[4 * c + 0]);
            float p1 = exp2fast(sT[4 * c + 1]);
            float p2 = exp2fast(sT[4 * c + 2]);
            float p3 = exp2fast(sT[4 * c + 3]);
            lrow += (p0 + p1) + (p2 + p3);
            union { unsigned u[2]; bf16x4 v; } pk;
            pk.u[0] = pack2bf(p0, p1);
            pk.u[1] = pack2bf(p2, p3);
            pfrag[c] = pk.v;
        }

        // O[q][d] += P.V over this wave's 32 keys
#pragma unroll
        for (int dt = 0; dt < 2; dt++)
#pragma unroll
            for (int c = 0; c < 4; c++) {
                bf16x4 vf = *(const bf16x4*)&Vl[32 * dt + l31][32 * kh + 8 * c + 4 * hi];
                o[dt][c & 1] = mfma32x8(pfrag[c], vf, o[dt][c & 1]);
            }
    }

    // combine across key-half wave pairs (two d-half chunks through Op), store
    lrow += __shfl_xor(lrow, 32); // both hi-halves hold full partial for q=l31
    float inv = 0.f;
#pragma unroll
    for (int dt = 0; dt < 2; dt++) {
        if (kh == 1) {
#pragma unroll
            for (int r = 0; r < 16; r++) {
                int qrl = (r & 3) + 8 * (r >> 2) + 4 * hi;
                Op[qh][qrl][l31] = o[dt][0][r] + o[dt][1][r];
            }
            if (dt == 0 && hi == 0) lp[qh][l31] = lrow;
        }
        __syncthreads();
        if (kh == 0) {
            if (dt == 0) {
                float l = lrow + lp[qh][l31] - padf; // remove pad-row p=1 terms
                inv = l > 0.f ? 1.f / l : 0.f;
            }
#pragma unroll
            for (int r = 0; r < 16; r++) {
                int qrl = (r & 3) + 8 * (r >> 2) + 4 * hi;
                float invr = __shfl(inv, qrl); // inv lives at lane q
                int qg = q0 + 32 * qh + qrl;
                size_t base = ((size_t)b * SEQ + qg) * DM + h * DK_;
                float v = o[dt][0][r] + o[dt][1][r] + Op[qh][qrl][l31];
                ctx[base + 32 * dt + l31] = f2bf(v * invr);
            }
        }
        __syncthreads(); // Op safe for next chunk
    }
}

extern "C" void kernel_launch(void* const* d_in, const int* in_sizes, int n_in,
                              void* d_out, int out_size, void* d_ws, size_t ws_size,
                              hipStream_t stream) {
    const float* q  = (const float*)d_in[0];
    const float* k  = (const float*)d_in[1];
    const float* v  = (const float*)d_in[2];
    const float* Wq = (const float*)d_in[3];
    const float* bq = (const float*)d_in[4];
    const float* Wk = (const float*)d_in[5];
    const float* bk = (const float*)d_in[6];
    const float* Wv = (const float*)d_in[7];
    const float* bv = (const float*)d_in[8];
    const float* Wo = (const float*)d_in[9];
    const float* bo = (const float*)d_in[10];
    const int* mask = (const int*)d_in[11];

    unsigned short* ws = (unsigned short*)d_ws;
    unsigned short* qb = ws;
    unsigned short* kb = ws + PER_IN;
    unsigned short* vb = ws + 2 * PER_IN;
    unsigned short* Qh = ws + 3 * PER_IN;
    unsigned short* Kh = ws + 4 * PER_IN;
    unsigned short* Vhn = ws + 5 * PER_IN;
    unsigned short* WtQKV = ws + 6 * PER_IN;
    unsigned short* WtO = WtQKV + (size_t)3 * DM * DM;
    unsigned short* Kc = kb;   // kb dead after QKV GEMM
    unsigned short* Vtc = vb;  // vb dead after QKV GEMM
    unsigned short* ctx = qb;  // qb dead after QKV GEMM
    // idx/nk scratch lives at the head of d_out: dead by the time the output
    // GEMM (the only d_out writer) runs; avoids aliasing live weight buffers.
    int* idx = (int*)d_out;
    int* nk = idx + B_DIM * SEQ;

    // prep: 9216 cvt blocks + 2304 transpose blocks + 2 scan blocks
    prep<<<dim3(11522), 256, 0, stream>>>(q, k, v, qb, kb, vb,
                                          Wq, Wk, Wv, Wo, WtQKV, mask, idx, nk);

    gemm128<1><<<dim3(MROWS / 128, 3 * DM / 128), 256, 0, stream>>>(
        qb, kb, vb, WtQKV, bq, bk, bv, Qh, Kh, Vhn);

    gatherKV<<<dim3(SEQ / 64, B_DIM * H_), 256, 0, stream>>>(Kh, Vhn, idx, nk, Kc, Vtc);

    attn_fa<<<dim3(SEQ / 64, B_DIM * H_), 256, 0, stream>>>(Qh, Kc, Vtc, nk, ctx);

    gemm128<0><<<dim3(MROWS / 128, DM / 128), 256, 0, stream>>>(
        ctx, ctx, ctx, WtO, bo, bo, bo, d_out, d_out, d_out);
}